// Round 7
// baseline (359.717 us; speedup 1.0000x reference)
//
#include <hip/hip_runtime.h>
#include <math.h>

typedef __bf16 bf16;
typedef __bf16 bf16x4 __attribute__((ext_vector_type(4)));
typedef __bf16 bf16x8 __attribute__((ext_vector_type(8)));
typedef float f32x4 __attribute__((ext_vector_type(4)));

#define MODE_QKV    0
#define MODE_SCORES 1
#define MODE_PV     2

__device__ inline void gload_lds16(const bf16* g, bf16* l) {
    __builtin_amdgcn_global_load_lds(
        (const __attribute__((address_space(1))) void*)g,
        (__attribute__((address_space(3))) void*)l, 16, 0, 0);
}

// ds_read_b128 with a compile-time immediate offset. asm-opaque: the
// compiler's DMA-alias waitcnt inserter can't see it (rule 18); lgkm waits
// are supplied manually, each followed by sched_barrier(0).
#define DSR(dst, base, imm)                                                 \
    asm volatile("ds_read_b128 %0, %1 offset:%2"                            \
        : "=v"(dst)                                                         \
        : "v"((const __attribute__((address_space(3))) bf16*)(base)),       \
          "i"(imm))

#define MF(i, j) acc[i][j] = __builtin_amdgcn_mfma_f32_16x16x32_bf16(       \
    af[i], bq[j], acc[i][j], 0, 0, 0);

// NT GEMM, 256x128 tile, BK=32, 4 waves (2M x 2N), per-wave 128x64 output,
// MFMA 16x16x32, RING-slot LDS ring, (RING-1)-ahead prefetch.
//   RING=3: 2-ahead, counted vmcnt(6) at tile end (tile t+1 landed, t+2
//           flying). 72 KiB LDS -> 2 blocks/CU.  Proven R5 config.
//   RING=2: 1-ahead, vmcnt(0) at tile end (costless: issued one full tile
//           ~1600cy earlier > HBM latency). 48 KiB LDS -> 3 blocks/CU.
// IMPORTANT: launch_bounds stays (256,2) for BOTH: at the measured 128
// VGPR the register file already permits 4 waves/SIMD, so occupancy is
// LDS-capped (RING=2 -> 3 blocks/CU). Forcing min-waves=3 (R6) squeezed
// the VGPR budget below the ~200 live regs -> regalloc spilled the
// asm-written fragments to scratch BEFORE the manual lgkmcnt(0) -> NaN.
// All 12 fragment reads per tile are ds_read_b128 base+offset:imm (zero
// per-tile VALU; swizzle term is lane-constant so base is loop-invariant).
// MFMA clusters gated by descending lgkmcnt(6)/(4)/(0); one barrier/tile.
// LDS chunk-XOR swizzle (proven 0-conflict): slot q of row r holds global
// 16B chunk q ^ ((r>>1)&3); staging pre-swizzles the global source address.
// MODE_QKV:    C = bf16(acc + bias[col])
// MODE_SCORES: C = bf16(exp(alpha*acc))
// MODE_PV:     split-K x2 (blockIdx.z = batch*2 + kHalf): fp32 HW-atomic
//              accumulate into pre-zeroed C (order-independent result).
template <int MODE, int NT, int RING>
__global__ __launch_bounds__(256, 2) void mfma_nt(
    const bf16* __restrict__ A, const bf16* __restrict__ B,
    const float* __restrict__ bias, void* __restrict__ Cv,
    int lda, int ldb, int ldc,
    long sA, long sB, long sC, float alpha)
{
    constexpr bool SPLIT = (MODE == MODE_PV);

    const int bz    = blockIdx.z;
    const int batch = SPLIT ? (bz >> 1) : bz;
    const int koff  = SPLIT ? (bz & 1) * (NT * 32) : 0;
    A += (long)batch * sA + koff;
    B += (long)batch * sB + koff;

    // RING slots: A 256x32 (8192 el = 16 KiB), B 128x32 (4096 el = 8 KiB)
    __shared__ bf16 As[RING * 8192] __attribute__((aligned(16)));
    __shared__ bf16 Bs[RING * 4096] __attribute__((aligned(16)));

    const int t  = threadIdx.x;
    const int m0 = blockIdx.y * 256;
    const int n0 = blockIdx.x * 128;

    const int lane = t & 63;
    const int wave = t >> 6;
    const int wr   = (wave >> 1) * 128;  // wave row origin (M)
    const int wc   = (wave & 1) * 64;    // wave col origin (N)
    const int fr   = lane & 15;
    const int kq8  = lane >> 4;

    // staging decomposition: chunk c -> row c>>2, slot c&3,
    // global k8-chunk = slot ^ ((row>>1)&3)
    const bf16* gA0; const bf16* gA1; const bf16* gA2; const bf16* gA3;
    const bf16* gB0; const bf16* gB1;
    {
        const int c0 = t,        r0 = c0 >> 2, h0 = ((c0 & 3) ^ ((r0 >> 1) & 3)) * 8;
        const int c1 = t + 256,  r1 = c1 >> 2, h1 = ((c1 & 3) ^ ((r1 >> 1) & 3)) * 8;
        const int c2 = t + 512,  r2 = c2 >> 2, h2 = ((c2 & 3) ^ ((r2 >> 1) & 3)) * 8;
        const int c3 = t + 768,  r3 = c3 >> 2, h3 = ((c3 & 3) ^ ((r3 >> 1) & 3)) * 8;
        gA0 = A + (long)(m0 + r0) * lda + h0;
        gA1 = A + (long)(m0 + r1) * lda + h1;
        gA2 = A + (long)(m0 + r2) * lda + h2;
        gA3 = A + (long)(m0 + r3) * lda + h3;
        gB0 = B + (long)(n0 + r0) * ldb + h0;
        gB1 = B + (long)(n0 + r1) * ldb + h1;
    }

    // fragment lane bases: addr = base + slot*SZ + frag*1024 (all immediates).
    // (r>>1)&3 == (fr>>1)&3 for every fragment row, so swz is lane-constant.
    const int swz = kq8 ^ ((fr >> 1) & 3);
    const bf16* pA = As + (wr + fr) * 32 + swz * 8;
    const bf16* pB = Bs + (wc + fr) * 32 + swz * 8;

    f32x4 acc[8][4] = {};
    bf16x8 af[8], bq[4];
    int kofs;

#define STAGE6(SS, ko)                                                      \
    gload_lds16(gA0 + (ko), &As[(SS) * 8192 + t * 8]);                      \
    gload_lds16(gA1 + (ko), &As[(SS) * 8192 + (t + 256) * 8]);              \
    gload_lds16(gA2 + (ko), &As[(SS) * 8192 + (t + 512) * 8]);              \
    gload_lds16(gA3 + (ko), &As[(SS) * 8192 + (t + 768) * 8]);              \
    gload_lds16(gB0 + (ko), &Bs[(SS) * 4096 + t * 8]);                      \
    gload_lds16(gB1 + (ko), &Bs[(SS) * 4096 + (t + 256) * 8]);

    // TB(CS, STG): one K-tile from slot CS.
    //   STG=1: stage next tile into slot (CS+RING-1)%RING, end with counted
    //          wait (RING=3: vmcnt(6); RING=2: vmcnt(0)) + barrier
    //   STG=0: no stage, end with vmcnt(0)+barrier
    //   STG=2: last tile: no stage, no wait, no barrier
#define TB(CS, STG) do {                                                    \
    if constexpr ((STG) == 1) {                                             \
        constexpr int SS = ((CS) + RING - 1) % RING;                        \
        STAGE6(SS, kofs);                                                   \
        kofs += 32;                                                         \
    }                                                                       \
    DSR(af[0], pA, (CS) * 16384 + 0);                                       \
    DSR(af[1], pA, (CS) * 16384 + 1024);                                    \
    DSR(af[2], pA, (CS) * 16384 + 2048);                                    \
    DSR(af[3], pA, (CS) * 16384 + 3072);                                    \
    DSR(bq[0], pB, (CS) * 8192 + 0);                                        \
    DSR(bq[1], pB, (CS) * 8192 + 1024);                                     \
    DSR(bq[2], pB, (CS) * 8192 + 2048);                                     \
    DSR(bq[3], pB, (CS) * 8192 + 3072);                                     \
    DSR(af[4], pA, (CS) * 16384 + 4096);                                    \
    DSR(af[5], pA, (CS) * 16384 + 5120);                                    \
    DSR(af[6], pA, (CS) * 16384 + 6144);                                    \
    DSR(af[7], pA, (CS) * 16384 + 7168);                                    \
    asm volatile("s_waitcnt lgkmcnt(6)" ::: "memory");                      \
    __builtin_amdgcn_sched_barrier(0);                                      \
    __builtin_amdgcn_s_setprio(1);                                          \
    MF(0,0) MF(0,1) MF(1,0) MF(1,1) MF(2,0) MF(2,1) MF(3,0) MF(3,1)         \
    asm volatile("s_waitcnt lgkmcnt(4)" ::: "memory");                      \
    __builtin_amdgcn_sched_barrier(0);                                      \
    MF(0,2) MF(0,3) MF(1,2) MF(1,3) MF(2,2) MF(2,3) MF(3,2) MF(3,3)         \
    asm volatile("s_waitcnt lgkmcnt(0)" ::: "memory");                      \
    __builtin_amdgcn_sched_barrier(0);                                      \
    MF(4,0) MF(4,1) MF(5,0) MF(5,1) MF(6,0) MF(6,1) MF(7,0) MF(7,1)         \
    MF(4,2) MF(4,3) MF(5,2) MF(5,3) MF(6,2) MF(6,3) MF(7,2) MF(7,3)         \
    __builtin_amdgcn_s_setprio(0);                                          \
    if constexpr ((STG) == 1) {                                             \
        if constexpr (RING == 3)                                            \
            asm volatile("s_waitcnt vmcnt(6)" ::: "memory");                \
        else                                                                \
            asm volatile("s_waitcnt vmcnt(0)" ::: "memory");                \
    } else if constexpr ((STG) == 0)                                        \
        asm volatile("s_waitcnt vmcnt(0)" ::: "memory");                    \
    if constexpr ((STG) != 2) __builtin_amdgcn_s_barrier();                 \
} while (0)

    if constexpr (RING == 3) {
        // prologue: stage tiles 0 (slot 0) and 1 (slot 1); tile-0 landed
        STAGE6(0, 0);
        STAGE6(1, 32);
        kofs = 64;
        asm volatile("s_waitcnt vmcnt(6)" ::: "memory");
        __builtin_amdgcn_s_barrier();

        static_assert(NT % 3 != 0, "peel pattern assumes NT%3 in {1,2}");
        if constexpr (NT % 3 == 2) {
            TB(0, 1); TB(1, 1);
            for (int g = 0; g < (NT - 5) / 3; ++g) { TB(2, 1); TB(0, 1); TB(1, 1); }
            TB(2, 1); TB(0, 0); TB(1, 2);
        } else {
            TB(0, 1);
            for (int g = 0; g < (NT - 4) / 3; ++g) { TB(1, 1); TB(2, 1); TB(0, 1); }
            TB(1, 1); TB(2, 0); TB(0, 2);
        }
    } else {
        // prologue: stage tile 0 (slot 0), landed
        STAGE6(0, 0);
        kofs = 32;
        asm volatile("s_waitcnt vmcnt(0)" ::: "memory");
        __builtin_amdgcn_s_barrier();

        static_assert(NT % 2 == 0, "2-slot peel assumes even NT");
        for (int g = 0; g < NT / 2 - 1; ++g) { TB(0, 1); TB(1, 1); }
        TB(0, 1); TB(1, 2);
    }
#undef TB
#undef STAGE6

    // C/D layout: col=lane&15, row=(lane>>4)*4+reg  [m89-verified]
    const int r4 = (lane >> 4) * 4;
    if constexpr (MODE == MODE_PV) {
        float* C = (float*)Cv + (long)batch * sC;
#pragma unroll
        for (int j = 0; j < 4; j++) {
            const int col = n0 + wc + j * 16 + fr;
#pragma unroll
            for (int i = 0; i < 8; i++)
#pragma unroll
                for (int r = 0; r < 4; r++) {
                    const long row = m0 + wr + i * 16 + r4 + r;
                    unsafeAtomicAdd(&C[row * ldc + col], acc[i][j][r]);
                }
        }
    } else {
        bf16* C = (bf16*)Cv + (long)batch * sC;
#pragma unroll
        for (int j = 0; j < 4; j++) {
            const int col = n0 + wc + j * 16 + fr;
            const float bv = (MODE == MODE_QKV) ? bias[col] : 0.f;
#pragma unroll
            for (int i = 0; i < 8; i++)
#pragma unroll
                for (int r = 0; r < 4; r++) {
                    const long row = m0 + wr + i * 16 + r4 + r;
                    float v = acc[i][j][r];
                    if constexpr (MODE == MODE_QKV)
                        C[row * ldc + col] = (bf16)(v + bv);
                    else
                        C[row * ldc + col] = (bf16)__expf(alpha * v);
                }
        }
    }
}

__global__ __launch_bounds__(256) void f32_to_bf16(
    const float* __restrict__ in, bf16* __restrict__ out, long n)
{
    long i = ((long)blockIdx.x * 256 + threadIdx.x) * 4;
    if (i < n) {
        float4 v = *(const float4*)(in + i);
        bf16x4 o = { (bf16)v.x, (bf16)v.y, (bf16)v.z, (bf16)v.w };
        *(bf16x4*)(out + i) = o;
    }
}

// Vt[b][e][s] = V[b][s][e]; V has ld 3072 (inside qkv), Vt ld 2048.
__global__ __launch_bounds__(256) void transpose_v(
    const bf16* __restrict__ V, bf16* __restrict__ Vt)
{
    __shared__ bf16 tile[32][33];
    const bf16* Vb  = V  + (long)blockIdx.z * 2048 * 3072;
    bf16*       Vtb = Vt + (long)blockIdx.z * 1024 * 2048;
    const int s0 = blockIdx.x * 32, e0 = blockIdx.y * 32;
    const int tx = threadIdx.x & 31, ty = threadIdx.x >> 5;
#pragma unroll
    for (int i = 0; i < 32; i += 8)
        tile[ty + i][tx] = Vb[(long)(s0 + ty + i) * 3072 + e0 + tx];
    __syncthreads();
#pragma unroll
    for (int i = 0; i < 32; i += 8)
        Vtb[(long)(e0 + ty + i) * 2048 + s0 + tx] = tile[tx][ty + i];
}

// Per row: sum exp-scores, write fp32 out1 = Pu/l, renormalize Pu IN PLACE (bf16).
__global__ __launch_bounds__(256) void norm_rows(
    bf16* __restrict__ Pu, float* __restrict__ out1)
{
    bf16* p  = Pu   + (long)blockIdx.x * 2048;
    float* o = out1 + (long)blockIdx.x * 2048;
    const int t = threadIdx.x;
    bf16x8 v = *(const bf16x8*)(p + t * 8);
    float f[8];
    float s = 0.f;
#pragma unroll
    for (int k = 0; k < 8; k++) { f[k] = (float)v[k]; s += f[k]; }
#pragma unroll
    for (int off = 32; off > 0; off >>= 1) s += __shfl_xor(s, off);
    __shared__ float red[4];
    const int wid = t >> 6, lane = t & 63;
    if (lane == 0) red[wid] = s;
    __syncthreads();
    s = red[0] + red[1] + red[2] + red[3];
    const float inv = 1.0f / s;
    float4 a, b;
    a.x = f[0] * inv; a.y = f[1] * inv; a.z = f[2] * inv; a.w = f[3] * inv;
    b.x = f[4] * inv; b.y = f[5] * inv; b.z = f[6] * inv; b.w = f[7] * inv;
    *(float4*)(o + t * 8)     = a;
    *(float4*)(o + t * 8 + 4) = b;
    bf16x8 w;
#pragma unroll
    for (int k = 0; k < 8; k++) w[k] = (bf16)(f[k] * inv);
    *(bf16x8*)(p + t * 8) = w;
}

extern "C" void kernel_launch(void* const* d_in, const int* in_sizes, int n_in,
                              void* d_out, int out_size, void* d_ws, size_t ws_size,
                              hipStream_t stream)
{
    const int B = 4, S = 2048, E = 1024;
    const float* X    = (const float*)d_in[0];   // [B,S,E]
    const float* W    = (const float*)d_in[1];   // [3E,E]
    const float* bias = (const float*)d_in[2];   // [3E]

    float* out0 = (float*)d_out;                  // [B,S,E]
    float* out1 = out0 + (long)B * S * E;         // [B,S,S]

    // ws layout (bytes):
    //   [ 0M, 48M)  qkvb bf16 [B*S, 3072]
    //   [48M, 64M)  Vt   bf16 [B][E][S]
    //   [64M, 96M)  Pu   bf16 [B][S][S]  (exp-scores; renormalized in place)
    //   Xb [64M,80M) and Wb [80M,86.3M) overlap Pu — dead before Pu is written.
    char* ws = (char*)d_ws;
    bf16* qkvb = (bf16*)(ws);
    bf16* Vt   = (bf16*)(ws + 50331648);
    bf16* Pu   = (bf16*)(ws + 67108864);
    bf16* Xb   = (bf16*)(ws + 67108864);
    bf16* Wb   = (bf16*)(ws + 83886080);

    f32_to_bf16<<<(long)B * S * E / 1024, 256, 0, stream>>>(X, Xb, (long)B * S * E);
    f32_to_bf16<<<(long)3 * E * E / 1024, 256, 0, stream>>>(W, Wb, (long)3 * E * E);

    // qkvb = bf16(X @ W^T + b)  [8192x3072, K=1024] -> 768 blocks
    // RING=2 (48 KiB LDS) -> 3 blocks/CU (LDS-capped; VGPR stays 128)
    mfma_nt<MODE_QKV, 32, 2><<<dim3(3 * E / 128, B * S / 256, 1), 256, 0, stream>>>(
        Xb, Wb, bias, qkvb, E, E, 3 * E, 0, 0, 0, 1.0f);

    // Vt = V^T per batch
    transpose_v<<<dim3(S / 32, E / 32, B), 256, 0, stream>>>(qkvb + 2 * E, Vt);

    // Pu = bf16(exp(Q @ K^T / 32))  [2048x2048, K=1024] x4 -> 512 blocks (RING=3)
    mfma_nt<MODE_SCORES, 32, 3><<<dim3(S / 128, S / 256, B), 256, 0, stream>>>(
        qkvb, qkvb + E, nullptr, Pu, 3 * E, 3 * E, S,
        (long)S * 3 * E, (long)S * 3 * E, (long)S * S, 0.03125f);

    // out1 = Pu / rowsum  (fp32); Pu <- normalized bf16 in place
    norm_rows<<<B * S, 256, 0, stream>>>(Pu, out1);

    // out0 = P @ V  (= Pu @ Vt^T, NT), split-K x2: z = batch*2 + kHalf,
    // fp32 HW-atomic accumulate into zeroed out0 (order-independent).
    hipMemsetAsync(out0, 0, (size_t)B * S * E * sizeof(float), stream);
    mfma_nt<MODE_PV, 32, 3><<<dim3(E / 128, S / 256, 2 * B), 256, 0, stream>>>(
        Pu, Vt, nullptr, out0, S, S, E,
        (long)S * S, (long)E * S, (long)S * E, 1.0f);
}

// Round 8
// 305.081 us; speedup vs baseline: 1.1791x; 1.1791x over previous
//
#include <hip/hip_runtime.h>
#include <math.h>

typedef __bf16 bf16;
typedef __bf16 bf16x4 __attribute__((ext_vector_type(4)));
typedef __bf16 bf16x8 __attribute__((ext_vector_type(8)));
typedef float f32x4 __attribute__((ext_vector_type(4)));

#define MODE_QKV    0
#define MODE_SCORES 1
#define MODE_PV     2

__device__ inline void gload_lds16(const bf16* g, bf16* l) {
    __builtin_amdgcn_global_load_lds(
        (const __attribute__((address_space(1))) void*)g,
        (__attribute__((address_space(3))) void*)l, 16, 0, 0);
}

// ds_read_b128 with a compile-time immediate offset. asm-opaque: the
// compiler's DMA-alias waitcnt inserter can't see it (rule 18); lgkm waits
// are supplied manually, each followed by sched_barrier(0).
#define DSR(dst, base, imm)                                                 \
    asm volatile("ds_read_b128 %0, %1 offset:%2"                            \
        : "=v"(dst)                                                         \
        : "v"((const __attribute__((address_space(3))) bf16*)(base)),       \
          "i"(imm))

// NT GEMM, 256x128 tile, BK=32, 4 waves (2M x 2N), per-wave 128x64 output,
// MFMA 16x16x32, 3-slot LDS ring, 2-ahead prefetch, counted vmcnt(6)
// (R5-proven substrate) + R8: in-wave software pipeline of LDS reads.
//
// Per tile t (slot C=t%3, parity P=t%2; frag sets alternate by parity so an
// in-flight ds_read never targets a register the current MFMAs still read):
//   1. issue 4 ds_read  afhi      (A rows 64..127, slot C)
//   2. lgkmcnt(4): alo[P]/bqq[P] (issued LAST tile, step 8) landed
//   3. MFMA upper 16  (alo[P] x bqq[P])
//   4. stage tile t+2 -> slot (C+2)%3   [6 global_load_lds]
//   5. lgkmcnt(0): afhi landed  (covered by step-3 MFMA wall)
//   6. vmcnt(6): tile t+1's stage (issued tile t-1) landed; t+2's flying
//      -- counted, never drains just-issued loads (R7 lesson)
//   7. s_barrier: t+1 slot visible to all waves; slot C free for t+3's
//      stage (issued only after this barrier by any wave -> WAR race-free,
//      since step 5 drained ALL this wave's slot-C reads pre-barrier)
//   8. issue 8 ds_read alo[P^1]/bqq[P^1] from slot (C+1)%3 (tile t+1)
//   9. MFMA lower 16  (afhi x bqq[P])   -- hides step-8 latency
// Every lgkm gate waits on reads issued >=1 MFMA-cluster earlier: ~zero
// exposed LDS latency.  Slot x parity period = 6 -> groups-of-6 unroll.
// LDS chunk-XOR swizzle (proven 0-conflict): slot q of row r holds global
// 16B chunk q ^ ((r>>1)&3); staging pre-swizzles the global source address.
// launch_bounds(256,2): VGPR cap 256 > ~225 live (R6 lesson: never squeeze
// the cap below live range of asm-written frags -> spill = NaN).
// MODE_QKV:    C = bf16(acc + bias[col])
// MODE_SCORES: C = bf16(exp(alpha*acc))
// MODE_PV:     C = fp32 acc (plain stores; R7: split-K atomics re-fetch C
//              through L2 -> +64MB HBM, PV 64->90us. Never again.)
template <int MODE, int NT>
__global__ __launch_bounds__(256, 2) void mfma_nt(
    const bf16* __restrict__ A, const bf16* __restrict__ B,
    const float* __restrict__ bias, void* __restrict__ Cv,
    int lda, int ldb, int ldc,
    long sA, long sB, long sC, float alpha)
{
    A += (long)blockIdx.z * sA;
    B += (long)blockIdx.z * sB;

    // 3 slots: A 256x32 (8192 el = 16 KiB), B 128x32 (4096 el = 8 KiB)
    __shared__ bf16 As[3 * 8192] __attribute__((aligned(16)));
    __shared__ bf16 Bs[3 * 4096] __attribute__((aligned(16)));

    const int t  = threadIdx.x;
    const int m0 = blockIdx.y * 256;
    const int n0 = blockIdx.x * 128;

    const int lane = t & 63;
    const int wave = t >> 6;
    const int wr   = (wave >> 1) * 128;  // wave row origin (M)
    const int wc   = (wave & 1) * 64;    // wave col origin (N)
    const int fr   = lane & 15;
    const int kq8  = lane >> 4;

    // staging decomposition: chunk c -> row c>>2, slot c&3,
    // global k8-chunk = slot ^ ((row>>1)&3)
    const bf16* gA0; const bf16* gA1; const bf16* gA2; const bf16* gA3;
    const bf16* gB0; const bf16* gB1;
    {
        const int c0 = t,        r0 = c0 >> 2, h0 = ((c0 & 3) ^ ((r0 >> 1) & 3)) * 8;
        const int c1 = t + 256,  r1 = c1 >> 2, h1 = ((c1 & 3) ^ ((r1 >> 1) & 3)) * 8;
        const int c2 = t + 512,  r2 = c2 >> 2, h2 = ((c2 & 3) ^ ((r2 >> 1) & 3)) * 8;
        const int c3 = t + 768,  r3 = c3 >> 2, h3 = ((c3 & 3) ^ ((r3 >> 1) & 3)) * 8;
        gA0 = A + (long)(m0 + r0) * lda + h0;
        gA1 = A + (long)(m0 + r1) * lda + h1;
        gA2 = A + (long)(m0 + r2) * lda + h2;
        gA3 = A + (long)(m0 + r3) * lda + h3;
        gB0 = B + (long)(n0 + r0) * ldb + h0;
        gB1 = B + (long)(n0 + r1) * ldb + h1;
    }

    // fragment lane bases: addr = base + slot*SZ + frag*1024B (immediates).
    // (r>>1)&3 == (fr>>1)&3 for every fragment row, so swz is lane-constant.
    const int swz = kq8 ^ ((fr >> 1) & 3);
    const bf16* pA = As + (wr + fr) * 32 + swz * 8;
    const bf16* pB = Bs + (wc + fr) * 32 + swz * 8;

    f32x4 acc[8][4] = {};
    bf16x8 afhi[4];        // A rows 64..127 of current tile (single set)
    bf16x8 alo[2][4];      // A rows 0..63, parity double-buffered
    bf16x8 bqq[2][4];      // B frags, parity double-buffered
    int kofs;

#define STAGE6(SS, ko)                                                      \
    gload_lds16(gA0 + (ko), &As[(SS) * 8192 + t * 8]);                      \
    gload_lds16(gA1 + (ko), &As[(SS) * 8192 + (t + 256) * 8]);              \
    gload_lds16(gA2 + (ko), &As[(SS) * 8192 + (t + 512) * 8]);              \
    gload_lds16(gA3 + (ko), &As[(SS) * 8192 + (t + 768) * 8]);              \
    gload_lds16(gB0 + (ko), &Bs[(SS) * 4096 + t * 8]);                      \
    gload_lds16(gB1 + (ko), &Bs[(SS) * 4096 + (t + 256) * 8]);

#define MFU(i, j, P) acc[i][j] = __builtin_amdgcn_mfma_f32_16x16x32_bf16(   \
    alo[P][i], bqq[P][j], acc[i][j], 0, 0, 0);
#define MFL(i, j, P) acc[4 + i][j] = __builtin_amdgcn_mfma_f32_16x16x32_bf16(\
    afhi[i], bqq[P][j], acc[4 + i][j], 0, 0, 0);

    // TBP(C, P, STG): tile with slot C, parity P.
    //   STG=1: steady (stage t+2, vmcnt(6), prefetch t+1 frags)
    //   STG=0: no stage, vmcnt(0), prefetch t+1 frags
    //   STG=2: last tile (no stage/wait/barrier/prefetch)
#define TBP(C, P, STG) do {                                                 \
    DSR(afhi[0], pA, (C) * 16384 + 4096);                                   \
    DSR(afhi[1], pA, (C) * 16384 + 5120);                                   \
    DSR(afhi[2], pA, (C) * 16384 + 6144);                                   \
    DSR(afhi[3], pA, (C) * 16384 + 7168);                                   \
    asm volatile("s_waitcnt lgkmcnt(4)" ::: "memory");                      \
    __builtin_amdgcn_sched_barrier(0);                                      \
    __builtin_amdgcn_s_setprio(1);                                          \
    MFU(0,0,P) MFU(0,1,P) MFU(1,0,P) MFU(1,1,P)                             \
    MFU(2,0,P) MFU(2,1,P) MFU(3,0,P) MFU(3,1,P)                             \
    MFU(0,2,P) MFU(0,3,P) MFU(1,2,P) MFU(1,3,P)                             \
    MFU(2,2,P) MFU(2,3,P) MFU(3,2,P) MFU(3,3,P)                             \
    __builtin_amdgcn_s_setprio(0);                                          \
    if constexpr ((STG) == 1) { STAGE6(((C) + 2) % 3, kofs); kofs += 32; }  \
    asm volatile("s_waitcnt lgkmcnt(0)" ::: "memory");                      \
    __builtin_amdgcn_sched_barrier(0);                                      \
    if constexpr ((STG) == 1)                                               \
        asm volatile("s_waitcnt vmcnt(6)" ::: "memory");                    \
    else if constexpr ((STG) == 0)                                          \
        asm volatile("s_waitcnt vmcnt(0)" ::: "memory");                    \
    if constexpr ((STG) != 2) {                                             \
        __builtin_amdgcn_s_barrier();                                       \
        DSR(alo[(P)^1][0], pA, (((C)+1)%3) * 16384 + 0);                    \
        DSR(alo[(P)^1][1], pA, (((C)+1)%3) * 16384 + 1024);                 \
        DSR(alo[(P)^1][2], pA, (((C)+1)%3) * 16384 + 2048);                 \
        DSR(alo[(P)^1][3], pA, (((C)+1)%3) * 16384 + 3072);                 \
        DSR(bqq[(P)^1][0], pB, (((C)+1)%3) * 8192 + 0);                     \
        DSR(bqq[(P)^1][1], pB, (((C)+1)%3) * 8192 + 1024);                  \
        DSR(bqq[(P)^1][2], pB, (((C)+1)%3) * 8192 + 2048);                  \
        DSR(bqq[(P)^1][3], pB, (((C)+1)%3) * 8192 + 3072);                  \
        __builtin_amdgcn_sched_barrier(0);                                  \
    }                                                                       \
    __builtin_amdgcn_s_setprio(1);                                          \
    MFL(0,0,P) MFL(0,1,P) MFL(1,0,P) MFL(1,1,P)                             \
    MFL(2,0,P) MFL(2,1,P) MFL(3,0,P) MFL(3,1,P)                             \
    MFL(0,2,P) MFL(0,3,P) MFL(1,2,P) MFL(1,3,P)                             \
    MFL(2,2,P) MFL(2,3,P) MFL(3,2,P) MFL(3,3,P)                             \
    __builtin_amdgcn_s_setprio(0);                                          \
} while (0)

    // prologue: stage tiles 0 (slot 0) and 1 (slot 1); tile-0 landed; then
    // pre-read tile 0's lower-A/B frags into parity set 0.
    STAGE6(0, 0);
    STAGE6(1, 32);
    kofs = 64;
    asm volatile("s_waitcnt vmcnt(6)" ::: "memory");
    __builtin_amdgcn_s_barrier();
    DSR(alo[0][0], pA, 0);
    DSR(alo[0][1], pA, 1024);
    DSR(alo[0][2], pA, 2048);
    DSR(alo[0][3], pA, 3072);
    DSR(bqq[0][0], pB, 0);
    DSR(bqq[0][1], pB, 1024);
    DSR(bqq[0][2], pB, 2048);
    DSR(bqq[0][3], pB, 3072);

    // slot x parity period = 6: {(0,0),(1,1),(2,0),(0,1),(1,0),(2,1)}
    static_assert(NT == 32 || NT == 64, "peel assumes NT in {32,64}");
    if constexpr (NT == 32) {
        for (int g = 0; g < 5; ++g) {   // tiles 0..29
            TBP(0,0,1); TBP(1,1,1); TBP(2,0,1);
            TBP(0,1,1); TBP(1,0,1); TBP(2,1,1);
        }
        TBP(0,0,0); TBP(1,1,2);         // tiles 30,31
    } else {
        for (int g = 0; g < 10; ++g) {  // tiles 0..59
            TBP(0,0,1); TBP(1,1,1); TBP(2,0,1);
            TBP(0,1,1); TBP(1,0,1); TBP(2,1,1);
        }
        TBP(0,0,1); TBP(1,1,1);         // tiles 60,61 (stage 62,63)
        TBP(2,0,0); TBP(0,1,2);         // tiles 62,63
    }
#undef TBP
#undef STAGE6
#undef MFU
#undef MFL

    // C/D layout: col=lane&15, row=(lane>>4)*4+reg  [m89-verified]
    const int r4 = (lane >> 4) * 4;
    if constexpr (MODE == MODE_PV) {
        float* C = (float*)Cv + (long)blockIdx.z * sC;
#pragma unroll
        for (int j = 0; j < 4; j++) {
            const int col = n0 + wc + j * 16 + fr;
#pragma unroll
            for (int i = 0; i < 8; i++)
#pragma unroll
                for (int r = 0; r < 4; r++) {
                    const long row = m0 + wr + i * 16 + r4 + r;
                    C[row * ldc + col] = acc[i][j][r];
                }
        }
    } else {
        bf16* C = (bf16*)Cv + (long)blockIdx.z * sC;
#pragma unroll
        for (int j = 0; j < 4; j++) {
            const int col = n0 + wc + j * 16 + fr;
            const float bv = (MODE == MODE_QKV) ? bias[col] : 0.f;
#pragma unroll
            for (int i = 0; i < 8; i++)
#pragma unroll
                for (int r = 0; r < 4; r++) {
                    const long row = m0 + wr + i * 16 + r4 + r;
                    float v = acc[i][j][r];
                    if constexpr (MODE == MODE_QKV)
                        C[row * ldc + col] = (bf16)(v + bv);
                    else
                        C[row * ldc + col] = (bf16)__expf(alpha * v);
                }
        }
    }
}

__global__ __launch_bounds__(256) void f32_to_bf16(
    const float* __restrict__ in, bf16* __restrict__ out, long n)
{
    long i = ((long)blockIdx.x * 256 + threadIdx.x) * 4;
    if (i < n) {
        float4 v = *(const float4*)(in + i);
        bf16x4 o = { (bf16)v.x, (bf16)v.y, (bf16)v.z, (bf16)v.w };
        *(bf16x4*)(out + i) = o;
    }
}

// Vt[b][e][s] = V[b][s][e]; V has ld 3072 (inside qkv), Vt ld 2048.
__global__ __launch_bounds__(256) void transpose_v(
    const bf16* __restrict__ V, bf16* __restrict__ Vt)
{
    __shared__ bf16 tile[32][33];
    const bf16* Vb  = V  + (long)blockIdx.z * 2048 * 3072;
    bf16*       Vtb = Vt + (long)blockIdx.z * 1024 * 2048;
    const int s0 = blockIdx.x * 32, e0 = blockIdx.y * 32;
    const int tx = threadIdx.x & 31, ty = threadIdx.x >> 5;
#pragma unroll
    for (int i = 0; i < 32; i += 8)
        tile[ty + i][tx] = Vb[(long)(s0 + ty + i) * 3072 + e0 + tx];
    __syncthreads();
#pragma unroll
    for (int i = 0; i < 32; i += 8)
        Vtb[(long)(e0 + ty + i) * 2048 + s0 + tx] = tile[tx][ty + i];
}

// Per row: sum exp-scores, write fp32 out1 = Pu/l, renormalize Pu IN PLACE (bf16).
__global__ __launch_bounds__(256) void norm_rows(
    bf16* __restrict__ Pu, float* __restrict__ out1)
{
    bf16* p  = Pu   + (long)blockIdx.x * 2048;
    float* o = out1 + (long)blockIdx.x * 2048;
    const int t = threadIdx.x;
    bf16x8 v = *(const bf16x8*)(p + t * 8);
    float f[8];
    float s = 0.f;
#pragma unroll
    for (int k = 0; k < 8; k++) { f[k] = (float)v[k]; s += f[k]; }
#pragma unroll
    for (int off = 32; off > 0; off >>= 1) s += __shfl_xor(s, off);
    __shared__ float red[4];
    const int wid = t >> 6, lane = t & 63;
    if (lane == 0) red[wid] = s;
    __syncthreads();
    s = red[0] + red[1] + red[2] + red[3];
    const float inv = 1.0f / s;
    float4 a, b;
    a.x = f[0] * inv; a.y = f[1] * inv; a.z = f[2] * inv; a.w = f[3] * inv;
    b.x = f[4] * inv; b.y = f[5] * inv; b.z = f[6] * inv; b.w = f[7] * inv;
    *(float4*)(o + t * 8)     = a;
    *(float4*)(o + t * 8 + 4) = b;
    bf16x8 w;
#pragma unroll
    for (int k = 0; k < 8; k++) w[k] = (bf16)(f[k] * inv);
    *(bf16x8*)(p + t * 8) = w;
}

extern "C" void kernel_launch(void* const* d_in, const int* in_sizes, int n_in,
                              void* d_out, int out_size, void* d_ws, size_t ws_size,
                              hipStream_t stream)
{
    const int B = 4, S = 2048, E = 1024;
    const float* X    = (const float*)d_in[0];   // [B,S,E]
    const float* W    = (const float*)d_in[1];   // [3E,E]
    const float* bias = (const float*)d_in[2];   // [3E]

    float* out0 = (float*)d_out;                  // [B,S,E]
    float* out1 = out0 + (long)B * S * E;         // [B,S,S]

    // ws layout (bytes):
    //   [ 0M, 48M)  qkvb bf16 [B*S, 3072]
    //   [48M, 64M)  Vt   bf16 [B][E][S]
    //   [64M, 96M)  Pu   bf16 [B][S][S]  (exp-scores; renormalized in place)
    //   Xb [64M,80M) and Wb [80M,86.3M) overlap Pu — dead before Pu is written.
    char* ws = (char*)d_ws;
    bf16* qkvb = (bf16*)(ws);
    bf16* Vt   = (bf16*)(ws + 50331648);
    bf16* Pu   = (bf16*)(ws + 67108864);
    bf16* Xb   = (bf16*)(ws + 67108864);
    bf16* Wb   = (bf16*)(ws + 83886080);

    f32_to_bf16<<<(long)B * S * E / 1024, 256, 0, stream>>>(X, Xb, (long)B * S * E);
    f32_to_bf16<<<(long)3 * E * E / 1024, 256, 0, stream>>>(W, Wb, (long)3 * E * E);

    // qkvb = bf16(X @ W^T + b)   [M=8192, N=3072, K=1024] -> 768 blocks
    mfma_nt<MODE_QKV, 32><<<dim3(3 * E / 128, B * S / 256, 1), 256, 0, stream>>>(
        Xb, Wb, bias, qkvb, E, E, 3 * E, 0, 0, 0, 1.0f);

    // Vt = V^T per batch
    transpose_v<<<dim3(S / 32, E / 32, B), 256, 0, stream>>>(qkvb + 2 * E, Vt);

    // Pu = bf16(exp(Q @ K^T / 32))  [2048x2048, K=1024] x4 -> 512 blocks
    mfma_nt<MODE_SCORES, 32><<<dim3(S / 128, S / 256, B), 256, 0, stream>>>(
        qkvb, qkvb + E, nullptr, Pu, 3 * E, 3 * E, S,
        (long)S * 3 * E, (long)S * 3 * E, (long)S * S, 0.03125f);

    // out1 = Pu / rowsum  (fp32); Pu <- normalized bf16 in place
    norm_rows<<<B * S, 256, 0, stream>>>(Pu, out1);

    // out0 = P @ V  (= Pu @ Vt^T, NT)  [2048x1024, K=2048] x4 -> 256 blocks
    mfma_nt<MODE_PV, 64><<<dim3(E / 128, S / 256, B), 256, 0, stream>>>(
        Pu, Vt, nullptr, out0, S, S, E,
        (long)S * S, (long)E * S, (long)S * E, 1.0f);
}

// Round 9
// 296.684 us; speedup vs baseline: 1.2125x; 1.0283x over previous
//
#include <hip/hip_runtime.h>
#include <math.h>

typedef __bf16 bf16;
typedef __bf16 bf16x4 __attribute__((ext_vector_type(4)));
typedef __bf16 bf16x8 __attribute__((ext_vector_type(8)));
typedef float f32x4 __attribute__((ext_vector_type(4)));

#define MODE_QKV    0
#define MODE_SCORES 1
#define MODE_PV     2

__device__ inline void gload_lds16(const bf16* g, bf16* l) {
    __builtin_amdgcn_global_load_lds(
        (const __attribute__((address_space(1))) void*)g,
        (__attribute__((address_space(3))) void*)l, 16, 0, 0);
}

// ds_read_b128 with a compile-time immediate offset. asm-opaque: the
// compiler's DMA-alias waitcnt inserter can't see it (rule 18); lgkm waits
// are supplied manually, each followed by sched_barrier(0).
#define DSR(dst, base, imm)                                                 \
    asm volatile("ds_read_b128 %0, %1 offset:%2"                            \
        : "=v"(dst)                                                         \
        : "v"((const __attribute__((address_space(3))) bf16*)(base)),       \
          "i"(imm))

#define MF(i, j) acc[i][j] = __builtin_amdgcn_mfma_f32_16x16x32_bf16(       \
    af[i], bq[j], acc[i][j], 0, 0, 0);

// NT GEMM, 256x128 tile, BK=32, *** 8 waves (4M x 2N), 512 threads ***,
// per-wave 64x64 output, MFMA 16x16x32, 3-slot LDS ring, 2-ahead prefetch,
// counted vmcnt(3).
// R9 rationale: R3/R5/R8 scheduling refinements all pinned at MfmaUtil~32%
// with 2 waves/SIMD (2 blocks x 4 waves). No pipe saturated -> latency/
// lockstep bound. Fix = more independent wave streams per SIMD: 8-wave
// blocks halve per-wave register state (acc 64 + frags ~60 VGPR ~= 124
// total <= 128) -> 4 waves/SIMD at 2 blocks/CU (LDS 72 KiB). PV (1
// block/CU) doubles from 1 to 2 waves/SIMD.
// NO launch_bounds min-waves forcing: R6 showed forcing the VGPR cap below
// the live range spills asm-written frags -> scratch stores race the
// untracked ds_read -> NaN. Natural allocation: worst case is neutral perf.
// All 8 fragment reads per tile are ds_read_b128 base+offset:imm (zero
// per-tile VALU; swizzle term is lane-constant so base is loop-invariant).
// MFMA clusters gated by descending lgkmcnt(2)/(0); one barrier/tile.
// LDS chunk-XOR swizzle (proven 0-conflict): slot q of row r holds global
// 16B chunk q ^ ((r>>1)&3); staging pre-swizzles the global source address.
// MODE_QKV:    C = bf16(acc + bias[col])
// MODE_SCORES: C = bf16(exp(alpha*acc))
// MODE_PV:     C = fp32 acc (plain stores; R7: split-K atomics -> +64MB HBM)
template <int MODE, int NT>
__global__ __launch_bounds__(512) void mfma_nt(
    const bf16* __restrict__ A, const bf16* __restrict__ B,
    const float* __restrict__ bias, void* __restrict__ Cv,
    int lda, int ldb, int ldc,
    long sA, long sB, long sC, float alpha)
{
    A += (long)blockIdx.z * sA;
    B += (long)blockIdx.z * sB;

    // 3 slots: A 256x32 (8192 el = 16 KiB), B 128x32 (4096 el = 8 KiB)
    __shared__ bf16 As[3 * 8192] __attribute__((aligned(16)));
    __shared__ bf16 Bs[3 * 4096] __attribute__((aligned(16)));

    const int t  = threadIdx.x;
    const int m0 = blockIdx.y * 256;
    const int n0 = blockIdx.x * 128;

    const int lane = t & 63;
    const int wave = t >> 6;
    const int wr   = (wave >> 1) * 64;   // wave row origin (M): 4 waves
    const int wc   = (wave & 1) * 64;    // wave col origin (N): 2 waves
    const int fr   = lane & 15;
    const int kq8  = lane >> 4;

    // staging decomposition (512 threads): A chunks c = t, t+512 (1024
    // chunks = 256 rows x 4); B chunks c = t (512 chunks = 128 rows x 4).
    // chunk c -> row c>>2, slot c&3, global k8-chunk = slot ^ ((row>>1)&3)
    const bf16* gA0; const bf16* gA1; const bf16* gB0;
    {
        const int c0 = t,        r0 = c0 >> 2, h0 = ((c0 & 3) ^ ((r0 >> 1) & 3)) * 8;
        const int c1 = t + 512,  r1 = c1 >> 2, h1 = ((c1 & 3) ^ ((r1 >> 1) & 3)) * 8;
        gA0 = A + (long)(m0 + r0) * lda + h0;
        gA1 = A + (long)(m0 + r1) * lda + h1;
        gB0 = B + (long)(n0 + r0) * ldb + h0;
    }

    // fragment lane bases: addr = base + slot*SZ + frag*1024B (immediates).
    // (r>>1)&3 == (fr>>1)&3 for every fragment row, so swz is lane-constant.
    const int swz = kq8 ^ ((fr >> 1) & 3);
    const bf16* pA = As + (wr + fr) * 32 + swz * 8;
    const bf16* pB = Bs + (wc + fr) * 32 + swz * 8;

    f32x4 acc[4][4] = {};
    bf16x8 af[4], bq[4];
    int kofs;

#define STAGE3(SS, ko)                                                      \
    gload_lds16(gA0 + (ko), &As[(SS) * 8192 + t * 8]);                      \
    gload_lds16(gA1 + (ko), &As[(SS) * 8192 + (t + 512) * 8]);              \
    gload_lds16(gB0 + (ko), &Bs[(SS) * 4096 + t * 8]);

    // TB(CS, STG): one K-tile from slot CS.
    //   STG=1: stage tile t+2 into slot (CS+2)%3, end with vmcnt(3)+barrier
    //   STG=0: no stage, end with vmcnt(0)+barrier
    //   STG=2: last tile: no stage, no wait, no barrier
#define TB(CS, STG) do {                                                    \
    DSR(af[0], pA, (CS) * 16384 + 0);                                       \
    DSR(af[1], pA, (CS) * 16384 + 1024);                                    \
    DSR(bq[0], pB, (CS) * 8192 + 0);                                        \
    DSR(bq[1], pB, (CS) * 8192 + 1024);                                     \
    DSR(bq[2], pB, (CS) * 8192 + 2048);                                     \
    DSR(bq[3], pB, (CS) * 8192 + 3072);                                     \
    DSR(af[2], pA, (CS) * 16384 + 2048);                                    \
    DSR(af[3], pA, (CS) * 16384 + 3072);                                    \
    asm volatile("s_waitcnt lgkmcnt(2)" ::: "memory");                      \
    __builtin_amdgcn_sched_barrier(0);                                      \
    __builtin_amdgcn_s_setprio(1);                                          \
    MF(0,0) MF(0,1) MF(1,0) MF(1,1)                                         \
    MF(0,2) MF(0,3) MF(1,2) MF(1,3)                                         \
    __builtin_amdgcn_s_setprio(0);                                          \
    if constexpr ((STG) == 1) { STAGE3(((CS) + 2) % 3, kofs); kofs += 32; } \
    asm volatile("s_waitcnt lgkmcnt(0)" ::: "memory");                      \
    __builtin_amdgcn_sched_barrier(0);                                      \
    __builtin_amdgcn_s_setprio(1);                                          \
    MF(2,0) MF(2,1) MF(3,0) MF(3,1)                                         \
    MF(2,2) MF(2,3) MF(3,2) MF(3,3)                                         \
    __builtin_amdgcn_s_setprio(0);                                          \
    if constexpr ((STG) == 1)                                               \
        asm volatile("s_waitcnt vmcnt(3)" ::: "memory");                    \
    else if constexpr ((STG) == 0)                                          \
        asm volatile("s_waitcnt vmcnt(0)" ::: "memory");                    \
    if constexpr ((STG) != 2) __builtin_amdgcn_s_barrier();                 \
} while (0)

    // prologue: stage tiles 0 (slot 0) and 1 (slot 1); tile-0 landed
    STAGE3(0, 0);
    STAGE3(1, 32);
    kofs = 64;
    asm volatile("s_waitcnt vmcnt(3)" ::: "memory");
    __builtin_amdgcn_s_barrier();

    static_assert(NT % 3 != 0, "peel pattern assumes NT%3 in {1,2}");
    if constexpr (NT % 3 == 2) {
        TB(0, 1); TB(1, 1);
        for (int g = 0; g < (NT - 5) / 3; ++g) { TB(2, 1); TB(0, 1); TB(1, 1); }
        TB(2, 1); TB(0, 0); TB(1, 2);
    } else {
        TB(0, 1);
        for (int g = 0; g < (NT - 4) / 3; ++g) { TB(1, 1); TB(2, 1); TB(0, 1); }
        TB(1, 1); TB(2, 0); TB(0, 2);
    }
#undef TB
#undef STAGE3

    // C/D layout: col=lane&15, row=(lane>>4)*4+reg  [m89-verified]
    const int r4 = (lane >> 4) * 4;
    if constexpr (MODE == MODE_PV) {
        float* C = (float*)Cv + (long)blockIdx.z * sC;
#pragma unroll
        for (int j = 0; j < 4; j++) {
            const int col = n0 + wc + j * 16 + fr;
#pragma unroll
            for (int i = 0; i < 4; i++)
#pragma unroll
                for (int r = 0; r < 4; r++) {
                    const long row = m0 + wr + i * 16 + r4 + r;
                    C[row * ldc + col] = acc[i][j][r];
                }
        }
    } else {
        bf16* C = (bf16*)Cv + (long)blockIdx.z * sC;
#pragma unroll
        for (int j = 0; j < 4; j++) {
            const int col = n0 + wc + j * 16 + fr;
            const float bv = (MODE == MODE_QKV) ? bias[col] : 0.f;
#pragma unroll
            for (int i = 0; i < 4; i++)
#pragma unroll
                for (int r = 0; r < 4; r++) {
                    const long row = m0 + wr + i * 16 + r4 + r;
                    float v = acc[i][j][r];
                    if constexpr (MODE == MODE_QKV)
                        C[row * ldc + col] = (bf16)(v + bv);
                    else
                        C[row * ldc + col] = (bf16)__expf(alpha * v);
                }
        }
    }
}

__global__ __launch_bounds__(256) void f32_to_bf16(
    const float* __restrict__ in, bf16* __restrict__ out, long n)
{
    long i = ((long)blockIdx.x * 256 + threadIdx.x) * 4;
    if (i < n) {
        float4 v = *(const float4*)(in + i);
        bf16x4 o = { (bf16)v.x, (bf16)v.y, (bf16)v.z, (bf16)v.w };
        *(bf16x4*)(out + i) = o;
    }
}

// Vt[b][e][s] = V[b][s][e]; V has ld 3072 (inside qkv), Vt ld 2048.
__global__ __launch_bounds__(256) void transpose_v(
    const bf16* __restrict__ V, bf16* __restrict__ Vt)
{
    __shared__ bf16 tile[32][33];
    const bf16* Vb  = V  + (long)blockIdx.z * 2048 * 3072;
    bf16*       Vtb = Vt + (long)blockIdx.z * 1024 * 2048;
    const int s0 = blockIdx.x * 32, e0 = blockIdx.y * 32;
    const int tx = threadIdx.x & 31, ty = threadIdx.x >> 5;
#pragma unroll
    for (int i = 0; i < 32; i += 8)
        tile[ty + i][tx] = Vb[(long)(s0 + ty + i) * 3072 + e0 + tx];
    __syncthreads();
#pragma unroll
    for (int i = 0; i < 32; i += 8)
        Vtb[(long)(e0 + ty + i) * 2048 + s0 + tx] = tile[tx][ty + i];
}

// Per row: sum exp-scores, write fp32 out1 = Pu/l, renormalize Pu IN PLACE (bf16).
__global__ __launch_bounds__(256) void norm_rows(
    bf16* __restrict__ Pu, float* __restrict__ out1)
{
    bf16* p  = Pu   + (long)blockIdx.x * 2048;
    float* o = out1 + (long)blockIdx.x * 2048;
    const int t = threadIdx.x;
    bf16x8 v = *(const bf16x8*)(p + t * 8);
    float f[8];
    float s = 0.f;
#pragma unroll
    for (int k = 0; k < 8; k++) { f[k] = (float)v[k]; s += f[k]; }
#pragma unroll
    for (int off = 32; off > 0; off >>= 1) s += __shfl_xor(s, off);
    __shared__ float red[4];
    const int wid = t >> 6, lane = t & 63;
    if (lane == 0) red[wid] = s;
    __syncthreads();
    s = red[0] + red[1] + red[2] + red[3];
    const float inv = 1.0f / s;
    float4 a, b;
    a.x = f[0] * inv; a.y = f[1] * inv; a.z = f[2] * inv; a.w = f[3] * inv;
    b.x = f[4] * inv; b.y = f[5] * inv; b.z = f[6] * inv; b.w = f[7] * inv;
    *(float4*)(o + t * 8)     = a;
    *(float4*)(o + t * 8 + 4) = b;
    bf16x8 w;
#pragma unroll
    for (int k = 0; k < 8; k++) w[k] = (bf16)(f[k] * inv);
    *(bf16x8*)(p + t * 8) = w;
}

extern "C" void kernel_launch(void* const* d_in, const int* in_sizes, int n_in,
                              void* d_out, int out_size, void* d_ws, size_t ws_size,
                              hipStream_t stream)
{
    const int B = 4, S = 2048, E = 1024;
    const float* X    = (const float*)d_in[0];   // [B,S,E]
    const float* W    = (const float*)d_in[1];   // [3E,E]
    const float* bias = (const float*)d_in[2];   // [3E]

    float* out0 = (float*)d_out;                  // [B,S,E]
    float* out1 = out0 + (long)B * S * E;         // [B,S,S]

    // ws layout (bytes):
    //   [ 0M, 48M)  qkvb bf16 [B*S, 3072]
    //   [48M, 64M)  Vt   bf16 [B][E][S]
    //   [64M, 96M)  Pu   bf16 [B][S][S]  (exp-scores; renormalized in place)
    //   Xb [64M,80M) and Wb [80M,86.3M) overlap Pu — dead before Pu is written.
    char* ws = (char*)d_ws;
    bf16* qkvb = (bf16*)(ws);
    bf16* Vt   = (bf16*)(ws + 50331648);
    bf16* Pu   = (bf16*)(ws + 67108864);
    bf16* Xb   = (bf16*)(ws + 67108864);
    bf16* Wb   = (bf16*)(ws + 83886080);

    f32_to_bf16<<<(long)B * S * E / 1024, 256, 0, stream>>>(X, Xb, (long)B * S * E);
    f32_to_bf16<<<(long)3 * E * E / 1024, 256, 0, stream>>>(W, Wb, (long)3 * E * E);

    // qkvb = bf16(X @ W^T + b)   [M=8192, N=3072, K=1024] -> 768 blocks
    mfma_nt<MODE_QKV, 32><<<dim3(3 * E / 128, B * S / 256, 1), 512, 0, stream>>>(
        Xb, Wb, bias, qkvb, E, E, 3 * E, 0, 0, 0, 1.0f);

    // Vt = V^T per batch
    transpose_v<<<dim3(S / 32, E / 32, B), 256, 0, stream>>>(qkvb + 2 * E, Vt);

    // Pu = bf16(exp(Q @ K^T / 32))  [2048x2048, K=1024] x4 -> 512 blocks
    mfma_nt<MODE_SCORES, 32><<<dim3(S / 128, S / 256, B), 512, 0, stream>>>(
        qkvb, qkvb + E, nullptr, Pu, 3 * E, 3 * E, S,
        (long)S * 3 * E, (long)S * 3 * E, (long)S * S, 0.03125f);

    // out1 = Pu / rowsum  (fp32); Pu <- normalized bf16 in place
    norm_rows<<<B * S, 256, 0, stream>>>(Pu, out1);

    // out0 = P @ V  (= Pu @ Vt^T, NT)  [2048x1024, K=2048] x4 -> 256 blocks
    mfma_nt<MODE_PV, 64><<<dim3(E / 128, S / 256, B), 512, 0, stream>>>(
        Pu, Vt, nullptr, out0, S, S, E,
        (long)S * S, (long)E * S, (long)S * E, 1.0f);
}